// Round 19
// baseline (38.341 us; speedup 1.0000x reference)
//
#include <hip/hip_runtime.h>

#define B_ 8
#define S_ 2048
#define D_ 128
#define NT_ 64      // S/32 kv tiles
#define FRAG_ 512   // shorts per fragment group (64 lanes * 8)

typedef __attribute__((ext_vector_type(4))) float f32x4;
typedef __attribute__((ext_vector_type(16))) float f32x16;
typedef __attribute__((ext_vector_type(8))) short bf16x8;
typedef __attribute__((ext_vector_type(4))) unsigned u32x4;
typedef __attribute__((ext_vector_type(2))) unsigned uint32x2;

#define MF(a, b, c) __builtin_amdgcn_mfma_f32_32x32x16_bf16(a, b, c, 0, 0, 0)

__device__ __forceinline__ short f2bf(float f) {
  union { float f; unsigned u; } x; x.f = f;
  unsigned r = x.u + 0x7FFFu + ((x.u >> 16) & 1u);
  return (short)(r >> 16);
}

__device__ __forceinline__ float exp2_hw(float x) {
  float r;
  asm("v_exp_f32 %0, %1" : "=v"(r) : "v"(x));
  return r;
}

__device__ __forceinline__ unsigned cvt_pk_bf16(float lo, float hi) {
  unsigned r;
  asm("v_cvt_pk_bf16_f32 %0, %1, %2" : "=v"(r) : "v"(lo), "v"(hi));
  return r;
}

__device__ __forceinline__ void plswap(unsigned& a, unsigned& b, int hi) {
#if __has_builtin(__builtin_amdgcn_permlane32_swap)
  uint32x2 r = __builtin_amdgcn_permlane32_swap(a, b, false, false);
  a = r[0]; b = r[1];
#else
  unsigned pa = (unsigned)__shfl_xor((int)a, 32, 64);
  unsigned pb = (unsigned)__shfl_xor((int)b, 32, 64);
  unsigned na = hi ? pb : a;
  unsigned nb = hi ? b : pa;
  a = na; b = nb;
#endif
}

__device__ __forceinline__ f32x16 zero16() {
  f32x16 v = {0.f,0.f,0.f,0.f,0.f,0.f,0.f,0.f,0.f,0.f,0.f,0.f,0.f,0.f,0.f,0.f};
  return v;
}

// async global->LDS DMA, 16B per lane: LDS gets base + lane*16 (linear).
__device__ __forceinline__ void dma16(const short* g, short* l) {
  __builtin_amdgcn_global_load_lds(
      (const __attribute__((address_space(1))) void*)g,
      (__attribute__((address_space(3))) void*)l, 16, 0, 0);
}

// ---- fused prep: Q,K,V -> MFMA-fragment-linear bf16; all global I/O coalesced.
__global__ __launch_bounds__(256) void prep_frag(
    const float* __restrict__ Q, const float* __restrict__ K,
    const float* __restrict__ V, short* __restrict__ Qf,
    short* __restrict__ Kf, short* __restrict__ Vf) {
  __shared__ short qt[32][136], kt[32][136], vt[32][136];
  const int b  = blockIdx.x & 7;    // batch == XCD of the consumer kernel
  const int st = blockIdx.x >> 3;
  const int t  = threadIdx.x;
  const int row = t >> 3, c0 = (t & 7) * 16;     // 64B/thread coalesced loads
  const size_t base = ((size_t)(b * S_ + st * 32 + row)) * D_ + c0;
  const float scq = 0.12751744553939605f;        // log2(e)/sqrt(128)

  #pragma unroll
  for (int i = 0; i < 4; ++i) {
    f32x4 q = *(const f32x4*)(Q + base + i * 4);
    f32x4 k = *(const f32x4*)(K + base + i * 4);
    f32x4 v = *(const f32x4*)(V + base + i * 4);
    #pragma unroll
    for (int jj = 0; jj < 4; ++jj) {
      qt[row][c0 + i * 4 + jj] = f2bf(q[jj] * scq);
      kt[row][c0 + i * 4 + jj] = f2bf(k[jj]);
      vt[row][c0 + i * 4 + jj] = f2bf(v[jj]);
    }
  }
  __syncthreads();

  const int l = t & 63, ln = l & 31, hi = l >> 5, w = t >> 6;
  const size_t gidx = (size_t)(b * NT_ + st) * 8;
  #pragma unroll
  for (int i = 0; i < 2; ++i) {
    const int m = w * 2 + i;
    bf16x8 qv = *(const bf16x8*)&qt[ln][m * 16 + hi * 8];
    bf16x8 kv = *(const bf16x8*)&kt[ln][m * 16 + hi * 8];
    *(bf16x8*)(Qf + (gidx + m) * FRAG_ + l * 8) = qv;
    *(bf16x8*)(Kf + (gidx + m) * FRAG_ + l * 8) = kv;
    const int d4 = m >> 1, h = m & 1;
    bf16x8 vv;
    #pragma unroll
    for (int jj = 0; jj < 8; ++jj) vv[jj] = vt[h * 16 + hi * 8 + jj][d4 * 32 + ln];
    *(bf16x8*)(Vf + (gidx + m) * FRAG_ + l * 8) = vv;
  }
}

// ---- main: 256 blocks = (batch, pair {j, 63-j}) processed CONCURRENTLY.
// 8 waves = 2 tile-subs x 4 kv-parities. Per iteration, the block stages 4 kv
// tiles (64 KB) into LDS via async DMA (double-buffered, 128 KB) and BOTH
// subs consume the same staged tiles -> K/V bytes shared 2x over 0..j; for
// s>j sub0 idles (SIMD load halves exactly when sharing drops -> uniform
// makespan). Merge epilogue overlays the staging LDS.
__global__ __launch_bounds__(512) void fattn_fwd(
    const short* __restrict__ Qf, const short* __restrict__ Kf,
    const short* __restrict__ Vf, float* __restrict__ Og) {
  const int idx  = blockIdx.x;                  // 0..255
  const int j    = idx >> 3;                    // pair index 0..31
  const int b    = idx & 7;                     // batch == XCD (L2 locality)
  const int tid  = threadIdx.x;
  const int w    = __builtin_amdgcn_readfirstlane(tid >> 6);  // wave 0..7
  const int sub  = w >> 2;                      // 0: tile j, 1: tile 63-j
  const int par  = w & 3;                       // kv parity
  const int lane = tid & 63;
  const int ln   = lane & 31;
  const int hi   = lane >> 5;
  const int lane8 = lane * 8;
  const int my_tile = sub ? (63 - j) : j;
  const int kmax = (67 - j) >> 2;               // ceil((64-j)/4): steps 0..63-j

  const short* Qfb = Qf + (size_t)b * (NT_ * 8 * FRAG_);
  const short* Kfb = Kf + (size_t)b * (NT_ * 8 * FRAG_);
  const short* Vfb = Vf + (size_t)b * (NT_ * 8 * FRAG_);
  float*       Ob  = Og + (size_t)b * S_ * D_;

  // 128 KB staging, overlaid by the 67.6 KB merge buffer after the loop
  __shared__ __align__(16) char Sraw[131072];
  short (*kvS)[4][8192] = (short (*)[4][8192])Sraw;      // [2][4][K 8KB | V 8KB]
  float (*ovl)[4][32][33] = (float (*)[4][32][33])Sraw;  // [4][4][32][33]
  __shared__ float lS[8][32], invLS[32];

  // wave w stages (tile-slot w>>1, K/V half w&1): 8 dma16 = 8 KB
#define STAGE(BUF, KK) do {                                              \
    const int s_ = 4 * (KK) + (w >> 1);                                  \
    if (s_ <= 63 - j) {                                                  \
      const short* src_ = ((w & 1) ? Vfb : Kfb)                          \
                          + (size_t)s_ * (8 * FRAG_) + lane8;            \
      short* dst_ = &kvS[BUF][w >> 1][(w & 1) * 4096];                   \
      _Pragma("unroll")                                                  \
      for (int m_ = 0; m_ < 8; ++m_)                                     \
        dma16(src_ + m_ * FRAG_, dst_ + m_ * 512);                       \
    }                                                                    \
  } while (0)

  // Q B-fragments for this wave's tile
  bf16x8 qb[8];
  {
    const short* qfp = Qfb + (size_t)my_tile * (8 * FRAG_);
    #pragma unroll
    for (int dt = 0; dt < 8; ++dt)
      qb[dt] = *(const bf16x8*)(qfp + dt * FRAG_ + lane8);
  }

  f32x16 o[4];
  #pragma unroll
  for (int i = 0; i < 4; ++i) o[i] = zero16();
  float l_part = 0.f;

  // prologue: stage iteration 0
  STAGE(0, 0);
  asm volatile("s_waitcnt vmcnt(0)" ::: "memory");
  __syncthreads();

  #pragma unroll 1
  for (int k = 0; k < kmax; ++k) {
    const int buf = k & 1;
    if (k + 1 < kmax) STAGE(buf ^ 1, k + 1);   // flies during this compute

    const int s = 4 * k + par;
    if (s <= my_tile) {
      const short* ls = &kvS[buf][par][0];

      // ---- S^T = K Q^T ----
      bf16x8 kb[8];
      #pragma unroll
      for (int dt = 0; dt < 8; ++dt)
        kb[dt] = *(const bf16x8*)(ls + dt * 512 + lane8);
      f32x16 sv = zero16();
      __builtin_amdgcn_s_setprio(1);
      #pragma unroll
      for (int dt = 0; dt < 8; ++dt) sv = MF(kb[dt], qb[dt], sv);
      __builtin_amdgcn_s_setprio(0);

      // ---- causal mask on this tile's diagonal step ----
      if (s == my_tile) {
        #pragma unroll
        for (int r = 0; r < 16; ++r) {
          const int kl = (r & 3) + 8 * (r >> 2) + 4 * hi;
          if (kl > ln) sv[r] = -512.0f;   // exp2 -> exact 0
        }
      }

      // ---- p = exp2(sv); per-lane row-sum ----
      float p[16];
      #pragma unroll
      for (int r = 0; r < 16; ++r) p[r] = exp2_hw(sv[r]);
      float ts[8];
      #pragma unroll
      for (int r = 0; r < 8; ++r) ts[r] = p[r] + p[r + 8];
      #pragma unroll
      for (int r = 0; r < 4; ++r) ts[r] = ts[r] + ts[r + 4];
      l_part += (ts[0] + ts[1]) + (ts[2] + ts[3]);

      // ---- P^T -> B-fragments (register-only) ----
      unsigned x0 = cvt_pk_bf16(p[0], p[1]),  x1 = cvt_pk_bf16(p[2], p[3]);
      unsigned y0 = cvt_pk_bf16(p[4], p[5]),  y1 = cvt_pk_bf16(p[6], p[7]);
      plswap(x0, y0, hi); plswap(x1, y1, hi);
      unsigned z0 = cvt_pk_bf16(p[8], p[9]),  z1 = cvt_pk_bf16(p[10], p[11]);
      unsigned w0 = cvt_pk_bf16(p[12], p[13]), w1 = cvt_pk_bf16(p[14], p[15]);
      plswap(z0, w0, hi); plswap(z1, w1, hi);
      u32x4 t0 = {x0, x1, y0, y1};
      u32x4 t1 = {z0, z1, w0, w1};
      bf16x8 pb0 = __builtin_bit_cast(bf16x8, t0);
      bf16x8 pb1 = __builtin_bit_cast(bf16x8, t1);

      // ---- O^T += V^T P^T (V fragments read JIT from LDS) ----
      __builtin_amdgcn_s_setprio(1);
      #pragma unroll
      for (int d4 = 0; d4 < 4; ++d4) {
        bf16x8 va0 = *(const bf16x8*)(ls + 4096 + (d4 * 2)     * 512 + lane8);
        bf16x8 va1 = *(const bf16x8*)(ls + 4096 + (d4 * 2 + 1) * 512 + lane8);
        o[d4] = MF(va0, pb0, o[d4]);
        o[d4] = MF(va1, pb1, o[d4]);
      }
      __builtin_amdgcn_s_setprio(0);
    }

    asm volatile("s_waitcnt vmcnt(0)" ::: "memory");
    __syncthreads();
  }

  // ---- merge: per-sub 4-parity reduction, two rounds over the overlay ----
  float l2 = l_part + __shfl_xor(l_part, 32, 64);
  if (hi == 0) lS[w][ln] = l2;
  __syncthreads();   // loop LDS reads done; safe to overlay

#define MERGE_ROUND(SUBV, Q0) do {                                       \
    if (sub == (SUBV)) {                                                 \
      const int wv_ = w - (SUBV) * 4;                                    \
      _Pragma("unroll")                                                  \
      for (int d4 = 0; d4 < 4; ++d4)                                     \
        _Pragma("unroll")                                                \
        for (int r = 0; r < 16; ++r)                                     \
          ovl[wv_][d4][ln][(r & 3) + 8 * (r >> 2) + 4 * hi] = o[d4][r];  \
    }                                                                    \
    __syncthreads();                                                     \
    if (tid < 32) {                                                      \
      const int base_ = (SUBV) * 4;                                      \
      invLS[tid] = 1.0f / (lS[base_][tid] + lS[base_ + 1][tid] +         \
                           lS[base_ + 2][tid] + lS[base_ + 3][tid]);     \
    }                                                                    \
    __syncthreads();                                                     \
    _Pragma("unroll")                                                    \
    for (int k2 = 0; k2 < 8; ++k2) {                                     \
      const int e = k2 * 512 + tid;                                      \
      const int row = e >> 7;                                            \
      const int col = e & 127;                                           \
      float acc = ovl[0][col >> 5][row][col & 31]                        \
                + ovl[1][col >> 5][row][col & 31]                        \
                + ovl[2][col >> 5][row][col & 31]                        \
                + ovl[3][col >> 5][row][col & 31];                       \
      Ob[(size_t)((Q0) + row) * D_ + col] = acc * invLS[row];            \
    }                                                                    \
    __syncthreads();                                                     \
  } while (0)

  MERGE_ROUND(0, j * 32);          // tile j
  MERGE_ROUND(1, (63 - j) * 32);   // tile 63-j

#undef MERGE_ROUND
#undef STAGE
}

extern "C" void kernel_launch(void* const* d_in, const int* in_sizes, int n_in,
                              void* d_out, int out_size, void* d_ws, size_t ws_size,
                              hipStream_t stream) {
  const float* Q = (const float*)d_in[0];
  const float* K = (const float*)d_in[1];
  const float* V = (const float*)d_in[2];
  float* O = (float*)d_out;

  short* Qf = (short*)d_ws;                    // 4 MiB
  short* Kf = Qf + (size_t)B_ * S_ * D_;       // 4 MiB
  short* Vf = Kf + (size_t)B_ * S_ * D_;       // 4 MiB

  prep_frag<<<B_ * NT_, 256, 0, stream>>>(Q, K, V, Qf, Kf, Vf);
  fattn_fwd<<<B_ * 32, 512, 0, stream>>>(Qf, Kf, Vf, O);
}